// Round 16
// baseline (151.994 us; speedup 1.0000x reference)
//
#include <hip/hip_runtime.h>
#include <math.h>

#define NN 31744        // total nodes B*NODES
#define NE 507904       // input edges (no self loops)
#define EP 1984         // edges per graph
#define NODES 124
#define NB 256          // graphs
#define CC 32           // channels
#define HC 128          // H*C
#define FEAT_DIM 316
#define NCLS 40
#define NC 3968         // NODES*CC
#define EXCAP 192

typedef __attribute__((ext_vector_type(8))) short bf16x8;
typedef __attribute__((ext_vector_type(4))) float f32x4;

#define LOG2E  1.44269504f
#define LOG2E5 0.28853901f   // 0.2 * log2(e)

__device__ __forceinline__ unsigned short f2bf(float f) {
    unsigned u = __float_as_uint(f);
    u = u + 0x7FFFu + ((u >> 16) & 1u);      // RNE
    return (unsigned short)(u >> 16);
}
__device__ __forceinline__ float bf2f(unsigned short s) {
    return __uint_as_float(((unsigned)s) << 16);
}

// ---------------- prep: lin1 W^T bf16 transpose + feat/bnacc zero ----------------
// blocks 0..495: wtrans ; blocks 496..559: zero feat layer-2 pool slots
__global__ __launch_bounds__(256) void prep_k(const float* __restrict__ W1,
                                              unsigned short* __restrict__ WT,
                                              float* __restrict__ bnacc,
                                              float* __restrict__ feat) {
    int t = threadIdx.x;
    if (blockIdx.x >= 496) {
        int idx = (blockIdx.x - 496) * 256 + t;   // 0..16383
        int g2 = idx >> 6, slot = idx & 63;
        feat[g2 * FEAT_DIM + 252 + slot] = 0.f;
        return;
    }
    __shared__ float tile[32][33];
    if (blockIdx.x == 0 && t < 192) bnacc[t] = 0.f;
    int kb = blockIdx.x >> 2, jb = blockIdx.x & 3;   // k-tile (124), j-tile (4)
    int tr = t >> 5, tc = t & 31;
    for (int r = tr; r < 32; r += 8) {
        int k = kb * 32 + r, j = jb * 32 + tc;
        tile[r][tc] = (j < 124) ? W1[k * 124 + j] : 0.f;
    }
    __syncthreads();
    for (int r = tr; r < 32; r += 8) {
        int j = jb * 32 + r, k = kb * 32 + tc;
        WT[(size_t)j * NC + k] = f2bf(tile[tc][r]);
    }
}

// ---------------- fused per-graph layer kernel ----------------
// layer 0 (lprev<0): builds mask/dup inline (writes global for layers 1,2)
// layers 1,2: fuse BN+relu+pool of previous layer during x staging
#define HS 136   // h plane row stride in shorts
#define TS 136   // hTall row stride
#define XS 40    // x / WT staging stride in shorts
#define ABS 136  // attB stride
#define PWS 40   // per-wave P slot row stride (shorts)

__global__ __launch_bounds__(1024, 1) void conv_graph(
    const float* __restrict__ xin, const float* __restrict__ W,
    const float* __restrict__ attl, const float* __restrict__ attr,
    const float* __restrict__ bias,
    unsigned* __restrict__ gmask, int* __restrict__ gdst, int* __restrict__ gdent,
    const int* __restrict__ ei,
    const float* __restrict__ bnprev, const float* __restrict__ gprev,
    const float* __restrict__ bprev, float* __restrict__ feat, int lprev,
    float* __restrict__ y, float* __restrict__ bnacc) {

    __shared__ short hpool[2 * 128 * HS];  // hbh | hbl (contiguous; mcnt overlay L0)
    __shared__ short hTall[128 * TS];      // h^T hi; WT overlay; locs overlay (layer 0)
    __shared__ short pwbuf[16 * 1280];     // per-wave 2xP slot; x overlay; exch overlay
    __shared__ short attBuf[16 * ABS];     // att_l/att_r B matrix
    __shared__ float ALs[4][128], ARs[4][128];
    __shared__ unsigned mask[128][4];
    __shared__ unsigned short dupst[136];
    __shared__ unsigned dupent[EXCAP];
    __shared__ float bias_s[32];
    __shared__ float bsum[8][32], bsq[8][32];
    __shared__ float pmean[32];
    __shared__ int pmax[32];
    __shared__ int cnt_s[128], pref_s[128];

    short* hbh = hpool;
    short* hbl = hpool + 128 * HS;
    int g = blockIdx.x, t = threadIdx.x, base = g * NODES;
    short* xh  = pwbuf;                   // [128][XS]
    short* xl  = pwbuf + 5120;
    short* WTh = hTall;                   // [128][XS]
    short* WTl = hTall + 5120;

    if (t < 32) { pmean[t] = 0.f; pmax[t] = 0; }
    __syncthreads();

    // ---- phase 1a: x staging (+BN/relu/pool fuse when lprev>=0), attB, bias ----
    {
        const float4* xsrc = (const float4*)(xin + (size_t)base * CC);
        for (int i = t; i < 992; i += 1024) {       // 124*32/4
            float4 v = xsrc[i];
            int n = i >> 3, c4 = i & 7;
            if (lprev >= 0) {
                float vv[4] = {v.x, v.y, v.z, v.w};
#pragma unroll
                for (int q = 0; q < 4; ++q) {
                    int c = c4 * 4 + q;
                    float mu = bnprev[c] * (1.f / NN);
                    float var = bnprev[32 + c] * (1.f / NN) - mu * mu;
                    float sc = rsqrtf(var + 1e-5f) * gprev[c];
                    float xv = (vv[q] - mu) * sc + bprev[c];
                    xv = fmaxf(xv, 0.f);
                    vv[q] = xv;
                    atomicAdd(&pmean[c], xv);
                    atomicMax(&pmax[c], __float_as_int(xv));
                }
                v.x = vv[0]; v.y = vv[1]; v.z = vv[2]; v.w = vv[3];
            }
            unsigned short h0 = f2bf(v.x), h1 = f2bf(v.y), h2 = f2bf(v.z), h3 = f2bf(v.w);
            unsigned short l0 = f2bf(v.x - bf2f(h0)), l1 = f2bf(v.y - bf2f(h1));
            unsigned short l2 = f2bf(v.z - bf2f(h2)), l3 = f2bf(v.w - bf2f(h3));
            uint2 ph; ph.x = ((unsigned)h1 << 16) | h0; ph.y = ((unsigned)h3 << 16) | h2;
            uint2 pl; pl.x = ((unsigned)l1 << 16) | l0; pl.y = ((unsigned)l3 << 16) | l2;
            *(uint2*)&xh[n * XS + c4 * 4] = ph;
            *(uint2*)&xl[n * XS + c4 * 4] = pl;
        }
        if (t < 4 * XS) { xh[124 * XS + t] = 0; xl[124 * XS + t] = 0; }
    }
    for (int i = t; i < 2048; i += 1024) {
        int n = i >> 7, k = i & 127;
        float v = 0.f;
        int hidx = n & 3;
        if (n < 8 && (k >> 5) == hidx)
            v = (n < 4) ? attl[hidx * 32 + (k & 31)] : attr[hidx * 32 + (k & 31)];
        attBuf[n * ABS + k] = (short)f2bf(v);
    }
    if (t < CC) bias_s[t] = bias[t];

    // ---- phase 1b: mask/dup — build inline (layer 0) or load (layers 1,2) ----
    if (lprev < 0) {
        unsigned* mcnt = (unsigned*)hpool;         // 61.5KB <= 69.6KB hpool
        int (*locs)[8] = (int(*)[8])hTall;
        for (int i = t; i < NODES * NODES; i += 1024) mcnt[i] = 0u;
        __syncthreads();
        for (int e = t; e < EP; e += 1024) {
            int s = ei[g * EP + e] - base;
            int d = ei[NE + g * EP + e] - base;
            atomicAdd(&mcnt[d * NODES + s], 1u);
        }
        __syncthreads();
        int nd = 0;
        if (t < 124) {
            unsigned m[4] = {0u, 0u, 0u, 0u};
            for (int s = 0; s < NODES; ++s) {
                unsigned c = mcnt[t * NODES + s] + (s == t ? 1u : 0u);   // self loop
                if (c) {
                    m[s >> 5] |= 1u << (s & 31);
                    if (c > 1u && nd < 8) { locs[t][nd] = (s << 8) | (int)c; nd++; }
                }
            }
            mask[t][0] = m[0]; mask[t][1] = m[1]; mask[t][2] = m[2]; mask[t][3] = m[3];
            uint4 mm; mm.x = m[0]; mm.y = m[1]; mm.z = m[2]; mm.w = m[3];
            *(uint4*)&gmask[(size_t)(base + t) * 4] = mm;
            cnt_s[t] = nd;
        } else if (t < 128) {
            cnt_s[t] = 0;
            mask[t][0] = 0u; mask[t][1] = 0u; mask[t][2] = 0u; mask[t][3] = 0u;
        }
        __syncthreads();
        if (t < 128) pref_s[t] = cnt_s[t];
        __syncthreads();
        for (int off = 1; off < 128; off <<= 1) {
            int v = (t >= off && t < 128) ? pref_s[t - off] : 0;
            __syncthreads();
            if (t < 128) pref_s[t] += v;
            __syncthreads();
        }
        if (t < 124) {
            int off = pref_s[t] - cnt_s[t];
            int offc = off < EXCAP ? off : EXCAP;
            dupst[t] = (unsigned short)offc;
            gdst[g * 132 + t] = offc;
            for (int j = 0; j < nd; ++j)
                if (off + j < EXCAP) {
                    dupent[off + j] = (unsigned)locs[t][j];
                    gdent[g * EXCAP + off + j] = locs[t][j];
                }
        } else if (t < 136) {
            int tot = pref_s[127];
            int totc = tot < EXCAP ? tot : EXCAP;
            dupst[t] = (unsigned short)totc;
            if (t == 124) gdst[g * 132 + 124] = totc;
        }
        __syncthreads();                   // locs (hTall) + mcnt (hpool) dead
    } else {
        if (t < 128) {
            if (t < 124) {
                uint4 m = *(const uint4*)&gmask[(size_t)(base + t) * 4];
                mask[t][0] = m.x; mask[t][1] = m.y; mask[t][2] = m.z; mask[t][3] = m.w;
            } else { mask[t][0] = 0u; mask[t][1] = 0u; mask[t][2] = 0u; mask[t][3] = 0u; }
        }
        if (t < 136) dupst[t] = (unsigned short)gdst[g * 132 + (t < 124 ? t : 124)];
        if (t >= 832 && t < 832 + EXCAP) dupent[t - 832] = (unsigned)gdent[g * EXCAP + (t - 832)];
        __syncthreads();                   // staging atomics (pmean/pmax) visible too
    }

    // ---- phase 1c: W staging (hTall overlay now free) + prev-layer feat write ----
    {
        int hc = t & 127, mq = t >> 7, ks = mq * 4;
        unsigned short hh4[4], ll4[4];
#pragma unroll
        for (int q = 0; q < 4; ++q) {
            float w = W[(ks + q) * HC + hc];
            hh4[q] = f2bf(w);
            ll4[q] = f2bf(w - bf2f(hh4[q]));
        }
        uint2 ph; ph.x = ((unsigned)hh4[1] << 16) | hh4[0]; ph.y = ((unsigned)hh4[3] << 16) | hh4[2];
        uint2 pl; pl.x = ((unsigned)ll4[1] << 16) | ll4[0]; pl.y = ((unsigned)ll4[3] << 16) | ll4[2];
        *(uint2*)&WTh[hc * XS + ks] = ph;
        *(uint2*)&WTl[hc * XS + ks] = pl;
    }
    if (lprev >= 0 && t < 32) {
        float* fp = feat + g * FEAT_DIM + NODES + lprev * 64;
        fp[t] = pmean[t] * (1.f / NODES);
        fp[32 + t] = __int_as_float(pmax[t]);
    }
    __syncthreads();

    int wv = t >> 6, l = t & 63;
    int l15 = l & 15, l4 = l >> 4;

    // ---- phase 2: H = x@W via split MFMA ----
#pragma unroll
    for (int j = 0; j < 4; ++j) {
        int idx = wv * 4 + j;
        int tr = idx >> 3, tc = idx & 7;
        bf16x8 ah = *(bf16x8*)&xh[(tr * 16 + l15) * XS + l4 * 8];
        bf16x8 al_ = *(bf16x8*)&xl[(tr * 16 + l15) * XS + l4 * 8];
        bf16x8 bh = *(bf16x8*)&WTh[(tc * 16 + l15) * XS + l4 * 8];
        bf16x8 bl_ = *(bf16x8*)&WTl[(tc * 16 + l15) * XS + l4 * 8];
        f32x4 z = {0.f, 0.f, 0.f, 0.f};
        f32x4 c0 = __builtin_amdgcn_mfma_f32_16x16x32_bf16(ah, bh, z, 0, 0, 0);
        f32x4 c1 = __builtin_amdgcn_mfma_f32_16x16x32_bf16(ah, bl_, z, 0, 0, 0);
        f32x4 c2 = __builtin_amdgcn_mfma_f32_16x16x32_bf16(al_, bh, z, 0, 0, 0);
        f32x4 c = (c0 + c1) + c2;
        int hc = tc * 16 + l15;
#pragma unroll
        for (int r = 0; r < 4; ++r) {
            int n = tr * 16 + l4 * 4 + r;
            float s = c[r];
            unsigned short hi = f2bf(s);
            hbh[n * HS + hc] = (short)hi;
            hbl[n * HS + hc] = (short)f2bf(s - bf2f(hi));
        }
    }
    __syncthreads();

    // ---- phase 3: AL/AR via MFMA || hTall transpose ----
    if (wv < 8) {
        f32x4 c = {0.f, 0.f, 0.f, 0.f};
#pragma unroll
        for (int kb = 0; kb < 4; ++kb) {
            bf16x8 a = *(bf16x8*)&hbh[(wv * 16 + l15) * HS + kb * 32 + l4 * 8];
            bf16x8 b = *(bf16x8*)&attBuf[l15 * ABS + kb * 32 + l4 * 8];
            c = __builtin_amdgcn_mfma_f32_16x16x32_bf16(a, b, c, 0, 0, 0);
        }
        if (l15 < 8) {
#pragma unroll
            for (int r = 0; r < 4; ++r) {
                int n = wv * 16 + l4 * 4 + r;
                if (l15 < 4) ALs[l15][n] = c[r];
                else         ARs[l15 - 4][n] = c[r];
            }
        }
    }
#pragma unroll
    for (int hh2 = 0; hh2 < 4; ++hh2) {
        int k = t & 31, n4 = t >> 5;
        unsigned short r4[4];
#pragma unroll
        for (int r = 0; r < 4; ++r)
            r4[r] = (unsigned short)hbh[(n4 * 4 + r) * HS + hh2 * 32 + k];
        uint2 pk;
        pk.x = ((unsigned)r4[1] << 16) | r4[0];
        pk.y = ((unsigned)r4[3] << 16) | r4[2];
        *(uint2*)&hTall[(hh2 * 32 + k) * TS + n4 * 4] = pk;
    }
    __syncthreads();

    // ---- phase 4: barrier-free pipelined attention body (sequential heads) ----
    int DJ = wv >> 1;
    float accA[4] = {0.f, 0.f, 0.f, 0.f};
    float accB[4] = {0.f, 0.f, 0.f, 0.f};
    {
        int hh0 = (wv & 1) * 2;
        short* pwb = pwbuf + wv * 1280;    // 2 slots x 640 shorts
        int dst = DJ * 16 + l15;
        uint4 mrow = *(uint4*)&mask[dst][0];
        unsigned mwords[4] = {mrow.x, mrow.y, mrow.z, mrow.w};
        unsigned cntp[8];
#pragma unroll
        for (int SI = 0; SI < 8; ++SI) {
            unsigned mw = (mwords[SI >> 1] >> ((SI & 1) * 16 + l4 * 4)) & 0xFu;
            cntp[SI] = (mw & 1u) | ((mw & 2u) << 7) | ((mw & 4u) << 14) | ((mw & 8u) << 21);
        }
        {
            int s0 = dupst[dst], s1 = dupst[dst + 1];
            for (int e = s0; e < s1; ++e) {
                unsigned ent = dupent[e];
                unsigned src = (ent >> 8) & 255u;
                unsigned SI = src >> 4;
                unsigned r = (src & 15u) - (unsigned)(l4 * 4);
                if (r < 4u) {
                    unsigned sh = 8u * r;
                    cntp[SI] = (cntp[SI] & ~(255u << sh)) | ((ent & 255u) << sh);
                }
            }
        }

#define GRAM(kb, slot) { \
    _Pragma("unroll") \
    for (int s2 = 0; s2 < 2; ++s2) { \
        int SI = (kb) * 2 + s2; \
        int ao = (SI * 16 + l15) * HS + hh * 32 + l4 * 8; \
        bf16x8 ah = *(bf16x8*)&hbh[ao]; \
        bf16x8 al_ = *(bf16x8*)&hbl[ao]; \
        f32x4 z2 = {0.f, 0.f, 0.f, 0.f}; \
        f32x4 c0 = __builtin_amdgcn_mfma_f32_16x16x32_bf16(ah, gb, z2, 0, 0, 0); \
        f32x4 c1 = __builtin_amdgcn_mfma_f32_16x16x32_bf16(ah, gl, z2, 0, 0, 0); \
        f32x4 c2 = __builtin_amdgcn_mfma_f32_16x16x32_bf16(al_, gb, z2, 0, 0, 0); \
        f32x4 c = (c0 + c1) + c2; \
        int src0 = SI * 16 + l4 * 4; \
        float4 al4 = *(float4*)&ALs[hh][src0]; \
        unsigned cp = cntp[SI]; \
        float pv[4]; \
        _Pragma("unroll") \
        for (int r = 0; r < 4; ++r) { \
            float e2 = __builtin_amdgcn_exp2f(-LOG2E * c[r]); \
            float sig = __builtin_amdgcn_rcpf(1.f + e2); \
            float a2 = (((const float*)&al4)[r] + ar) * sig; \
            float m = fmaxf(a2 * LOG2E, a2 * LOG2E5); \
            float cr = (float)((cp >> (8 * r)) & 255u); \
            pv[r] = __builtin_amdgcn_exp2f(m) * cr; \
        } \
        sden += (pv[0] + pv[1]) + (pv[2] + pv[3]); \
        unsigned w0_, w1_; \
        asm("v_cvt_pk_bf16_f32 %0, %1, %2" : "=v"(w0_) : "v"(pv[0]), "v"(pv[1])); \
        asm("v_cvt_pk_bf16_f32 %0, %1, %2" : "=v"(w1_) : "v"(pv[2]), "v"(pv[3])); \
        uint2 pk_; pk_.x = w0_; pk_.y = w1_; \
        *(uint2*)&pwb[(slot) * 640 + l15 * PWS + s2 * 16 + l4 * 4] = pk_; \
    } }

#define PVOP(kb, slot) { \
    bf16x8 a = *(bf16x8*)&pwb[(slot) * 640 + l15 * PWS + l4 * 8]; \
    bf16x8 b0 = *(bf16x8*)&hTall[(hh * 32 + l15) * TS + (kb) * 32 + l4 * 8]; \
    bf16x8 b1 = *(bf16x8*)&hTall[(hh * 32 + 16 + l15) * TS + (kb) * 32 + l4 * 8]; \
    num0 = __builtin_amdgcn_mfma_f32_16x16x32_bf16(a, b0, num0, 0, 0, 0); \
    num1 = __builtin_amdgcn_mfma_f32_16x16x32_bf16(a, b1, num1, 0, 0, 0); }

#pragma unroll
        for (int jj = 0; jj < 2; ++jj) {
            int hh = hh0 + jj;
            bf16x8 gb = *(bf16x8*)&hbh[dst * HS + hh * 32 + l4 * 8];
            bf16x8 gl = *(bf16x8*)&hbl[dst * HS + hh * 32 + l4 * 8];
            float ar = ARs[hh][dst];
            float sden = 0.f;
            f32x4 num0 = {0.f, 0.f, 0.f, 0.f};
            f32x4 num1 = {0.f, 0.f, 0.f, 0.f};
            GRAM(0, 0);
            GRAM(1, 1); PVOP(0, 0);
            GRAM(2, 0); PVOP(1, 1);
            GRAM(3, 1); PVOP(2, 0);
            PVOP(3, 1);
            sden += __shfl_xor(sden, 16, 64);
            sden += __shfl_xor(sden, 32, 64);
#pragma unroll
            for (int r = 0; r < 4; ++r) {
                float dn = __shfl(sden, l4 * 4 + r, 64) + 1e-16f;
                accA[r] += ((float*)&num0)[r] / dn;
                accB[r] += ((float*)&num1)[r] / dn;
            }
        }
#undef GRAM
#undef PVOP
    }
    __syncthreads();

    // ---- phase 5: pair1 -> exchange ----
    float* exch = (float*)pwbuf;
    if (wv & 1) {
#pragma unroll
        for (int r = 0; r < 4; ++r) {
            exch[DJ * 512 + l15 * 16 + l4 * 4 + r] = accA[r];
            exch[DJ * 512 + 256 + l15 * 16 + l4 * 4 + r] = accB[r];
        }
    }
    __syncthreads();

    // ---- phase 6: pair0 combine + y store + BN partials ----
    if (!(wv & 1)) {
        float sA = 0.f, qA = 0.f, sB = 0.f, qB = 0.f;
#pragma unroll
        for (int r = 0; r < 4; ++r) {
            int n = DJ * 16 + l4 * 4 + r;
            float a = accA[r] + exch[DJ * 512 + l15 * 16 + l4 * 4 + r];
            float b = accB[r] + exch[DJ * 512 + 256 + l15 * 16 + l4 * 4 + r];
            a = 0.25f * a + bias_s[l15];
            b = 0.25f * b + bias_s[16 + l15];
            if (n < NODES) {
                y[(size_t)(base + n) * CC + l15] = a;
                y[(size_t)(base + n) * CC + 16 + l15] = b;
                sA += a; qA += a * a; sB += b; qB += b * b;
            }
        }
        sA += __shfl_xor(sA, 16, 64); sA += __shfl_xor(sA, 32, 64);
        qA += __shfl_xor(qA, 16, 64); qA += __shfl_xor(qA, 32, 64);
        sB += __shfl_xor(sB, 16, 64); sB += __shfl_xor(sB, 32, 64);
        qB += __shfl_xor(qB, 16, 64); qB += __shfl_xor(qB, 32, 64);
        if (l < 16) {
            bsum[DJ][l15] = sA; bsum[DJ][16 + l15] = sB;
            bsq[DJ][l15] = qA;  bsq[DJ][16 + l15] = qB;
        }
    }
    __syncthreads();
    if (t < CC) {
        float S = 0.f, Q = 0.f;
#pragma unroll
        for (int w = 0; w < 8; ++w) { S += bsum[w][t]; Q += bsq[w][t]; }
        atomicAdd(&bnacc[t], S);
        atomicAdd(&bnacc[CC + t], Q);
    }
}

// ---------------- classifier head ----------------
#define L1_KS 4
#define L1_KC 992    // NC / 4 = 31 K-steps of 32 (31 nodes per slice)
#define XP 1000      // Xs row stride in shorts
// fused: layer-2 BN+relu (from fp32 y) during staging + layer-2 pool + GEMM
__global__ __launch_bounds__(512) void lin1_mfma(const float* __restrict__ Y,
                                                 const float* __restrict__ bnacc,
                                                 const float* __restrict__ bng,
                                                 const float* __restrict__ bnb,
                                                 const unsigned short* __restrict__ WT,
                                                 float* __restrict__ part,
                                                 float* __restrict__ feat) {
    __shared__ unsigned short Xs[16 * XP];   // 32 KB
    __shared__ float smu[32], ssc[32], sbt[32];
    int mt = blockIdx.x >> 2, kp = blockIdx.x & 3;
    int t = threadIdx.x;
    if (t < 32) {
        float mu = bnacc[128 + t] * (1.f / NN);
        float var = bnacc[160 + t] * (1.f / NN) - mu * mu;
        smu[t] = mu;
        ssc[t] = rsqrtf(var + 1e-5f) * bng[2 * CC + t];   // layer-2 gamma
        sbt[t] = bnb[2 * CC + t];                          // layer-2 beta
    }
    __syncthreads();
    int M0 = mt * 16, k0 = kp * L1_KC;
    for (int i = t; i < 16 * 248; i += 512) {    // 248 float4 per row slice
        int r = i / 248, c4 = i - r * 248;
        float4 v = *(const float4*)&Y[(size_t)(M0 + r) * NC + k0 + c4 * 4];
        int cb = (c4 * 4) & 31;
        float vv[4] = {v.x, v.y, v.z, v.w};
        unsigned short hb[4];
#pragma unroll
        for (int q = 0; q < 4; ++q) {
            int c = cb + q;
            float xv = fmaxf((vv[q] - smu[c]) * ssc[c] + sbt[c], 0.f);
            hb[q] = f2bf(xv);
        }
        uint2 pk;
        pk.x = ((unsigned)hb[1] << 16) | hb[0];
        pk.y = ((unsigned)hb[3] << 16) | hb[2];
        *(uint2*)&Xs[r * XP + c4 * 4] = pk;
    }
    __syncthreads();
    // layer-2 pool partials (atomic merge across the 4 kp blocks)
    {
        int gl = t >> 5, ch = t & 31;
        float s = 0.f, mx = 0.f;
        for (int nd2 = 0; nd2 < 31; ++nd2) {
            float v = bf2f(Xs[gl * XP + nd2 * 32 + ch]);
            s += v; mx = fmaxf(mx, v);
        }
        float* fp = feat + (size_t)(M0 + gl) * FEAT_DIM + 252;
        atomicAdd(&fp[ch], s * (1.f / NODES));
        atomicMax((int*)&fp[32 + ch], __float_as_int(mx));
    }
    int wv = t >> 6, l = t & 63, l15 = l & 15, l4 = l >> 4;
    int N0 = wv * 16;
    f32x4 acc = {0.f, 0.f, 0.f, 0.f};
#pragma unroll 4
    for (int kk = 0; kk < 31; ++kk) {
        bf16x8 a = *(bf16x8*)&Xs[l15 * XP + kk * 32 + l4 * 8];
        bf16x8 b = *(const bf16x8*)&WT[(size_t)(N0 + l15) * NC + k0 + kk * 32 + l4 * 8];
        acc = __builtin_amdgcn_mfma_f32_16x16x32_bf16(a, b, acc, 0, 0, 0);
    }
    if (N0 + l15 < 124) {
#pragma unroll
        for (int r = 0; r < 4; ++r)
            part[(size_t)kp * NB * 124 + (M0 + l4 * 4 + r) * 124 + N0 + l15] = acc[r];
    }
}

// fused: K-part reduce + bias + BN + relu -> feat[., 0..123]
__global__ __launch_bounds__(512) void bn1_fused(const float* __restrict__ part,
                                                 const float* __restrict__ b,
                                                 const float* __restrict__ gamma,
                                                 const float* __restrict__ beta,
                                                 float* __restrict__ out1,
                                                 float* __restrict__ feat) {
    __shared__ float ps[4][124], pq[4][124], smu[124], ssc[124], sbt[124];
    int t = threadIdx.x;
    int c = t & 127, seg = t >> 7;
    float s = 0.f, q = 0.f;
    if (c < 124) {
        float bb = b[c];
        for (int r = seg * 64; r < seg * 64 + 64; ++r) {
            int i = r * 124 + c;
            float v = bb + part[i] + part[NB * 124 + i]
                    + part[2 * NB * 124 + i] + part[3 * NB * 124 + i];
            out1[i] = v;
            s += v; q += v * v;
        }
        ps[seg][c] = s; pq[seg][c] = q;
    }
    __syncthreads();
    if (t < 124) {
        float S = ps[0][t] + ps[1][t] + ps[2][t] + ps[3][t];
        float Q = pq[0][t] + pq[1][t] + pq[2][t] + pq[3][t];
        float mu = S * (1.f / NB);
        float var = Q * (1.f / NB) - mu * mu;
        smu[t] = mu; ssc[t] = rsqrtf(var + 1e-5f) * gamma[t]; sbt[t] = beta[t];
    }
    __syncthreads();
    if (c < 124) {
        for (int r = seg * 64; r < seg * 64 + 64; ++r) {
            float v = (out1[r * 124 + c] - smu[c]) * ssc[c] + sbt[c];
            feat[r * FEAT_DIM + c] = fmaxf(v, 0.f);
        }
    }
}

__global__ void lin2_k(const float* __restrict__ feat, const float* __restrict__ W,
                       const float* __restrict__ b, float* __restrict__ out) {
    __shared__ float psum[8][40];
    int g = blockIdx.x;
    int t = threadIdx.x;
    int j = t % 40, u = t / 40;
    if (u < 8) {
        int k0 = u * 40, k1 = (u == 7) ? FEAT_DIM : k0 + 40;
        float s = 0.f;
        for (int k = k0; k < k1; ++k) s += feat[g * FEAT_DIM + k] * W[k * NCLS + j];
        psum[u][j] = s;
    }
    __syncthreads();
    if (t < NCLS) {
        float s = b[t];
#pragma unroll
        for (int u2 = 0; u2 < 8; ++u2) s += psum[u2][t];
        out[g * NCLS + t] = s;
    }
}

extern "C" void kernel_launch(void* const* d_in, const int* in_sizes, int n_in,
                              void* d_out, int out_size, void* d_ws, size_t ws_size,
                              hipStream_t stream) {
    const float* x      = (const float*)d_in[0];
    const int*   ei     = (const int*)d_in[1];
    const float* conv_W = (const float*)d_in[3];
    const float* att_l  = (const float*)d_in[4];
    const float* att_r  = (const float*)d_in[5];
    const float* conv_b = (const float*)d_in[6];
    const float* bn_g   = (const float*)d_in[7];
    const float* bn_b   = (const float*)d_in[8];
    const float* lin1_W = (const float*)d_in[9];
    const float* lin1_b = (const float*)d_in[10];
    const float* bn1_g  = (const float*)d_in[11];
    const float* bn1_b  = (const float*)d_in[12];
    const float* lin2_W = (const float*)d_in[13];
    const float* lin2_b = (const float*)d_in[14];

    float* ws = (float*)d_ws;
    float* y = ws;                                           // NN*32 fp32
    float* bnacc = y + (size_t)NN * CC;                      // 192
    float* feat  = bnacc + 192;                              // NB*316
    float* out1  = feat + NB * FEAT_DIM;                     // NB*124
    float* part  = out1 + NB * 124;                          // 4*NB*124
    unsigned short* WT = (unsigned short*)(part + L1_KS * NB * 124);  // 128*3968 bf16
    unsigned* gmask = (unsigned*)(WT + (size_t)128 * NC);    // NN*4
    int* gdst  = (int*)(gmask + (size_t)NN * 4);             // NB*132
    int* gdent = gdst + NB * 132;                            // NB*EXCAP

    prep_k<<<560, 256, 0, stream>>>(lin1_W, WT, bnacc, feat);

    const float* xin = x;
    for (int l = 0; l < 3; ++l) {
        const float* bnprev = (l == 0) ? nullptr : bnacc + (l - 1) * 64;
        const float* gprev  = (l == 0) ? bn_g : bn_g + (l - 1) * CC;
        const float* bprev  = (l == 0) ? bn_b : bn_b + (l - 1) * CC;
        conv_graph<<<NB, 1024, 0, stream>>>(xin, conv_W + l * CC * HC,
                                            att_l + l * HC, att_r + l * HC,
                                            conv_b + l * CC, gmask, gdst, gdent, ei,
                                            bnprev, gprev, bprev, feat, l - 1,
                                            y, bnacc + l * 64);
        xin = y;
    }

    lin1_mfma<<<64, 512, 0, stream>>>(y, bnacc, bn_g, bn_b, WT, part, feat);
    bn1_fused<<<1, 512, 0, stream>>>(part, lin1_b, bn1_g, bn1_b, out1, feat);
    lin2_k<<<NB, 320, 0, stream>>>(feat, lin2_W, lin2_b, (float*)d_out);
}

// Round 17
// 144.606 us; speedup vs baseline: 1.0511x; 1.0511x over previous
//
#include <hip/hip_runtime.h>
#include <math.h>

#define NN 31744        // total nodes B*NODES
#define NE 507904       // input edges (no self loops)
#define EP 1984         // edges per graph
#define NODES 124
#define NB 256          // graphs
#define CC 32           // channels
#define HC 128          // H*C
#define FEAT_DIM 316
#define NCLS 40
#define NC 3968         // NODES*CC
#define EXCAP 192

typedef __attribute__((ext_vector_type(8))) short bf16x8;
typedef __attribute__((ext_vector_type(4))) float f32x4;

#define LOG2E  1.44269504f
#define LOG2E5 0.28853901f   // 0.2 * log2(e)

__device__ __forceinline__ unsigned short f2bf(float f) {
    unsigned u = __float_as_uint(f);
    u = u + 0x7FFFu + ((u >> 16) & 1u);      // RNE
    return (unsigned short)(u >> 16);
}
__device__ __forceinline__ float bf2f(unsigned short s) {
    return __uint_as_float(((unsigned)s) << 16);
}

// ---------------- per-graph mask + duplicate-edge build (layer-invariant) -------------
__global__ __launch_bounds__(256) void mask_build(const int* __restrict__ ei,
                                                  unsigned* __restrict__ gmask,
                                                  int* __restrict__ gdst,
                                                  int* __restrict__ gdent,
                                                  float* __restrict__ bnacc) {
    __shared__ unsigned mcnt[NODES * NODES];   // 61.5 KB
    __shared__ int cnt[128], pref[128];
    __shared__ int locs[124][8];
    int g = blockIdx.x, t = threadIdx.x;
    if (g == 0 && t < 192) bnacc[t] = 0.f;     // zero all 3 layers' BN accumulators
    for (int i = t; i < NODES * NODES; i += 256) mcnt[i] = 0u;
    __syncthreads();
    for (int e = t; e < EP; e += 256) {
        int s = ei[g * EP + e] - g * NODES;
        int d = ei[NE + g * EP + e] - g * NODES;
        atomicAdd(&mcnt[d * NODES + s], 1u);
    }
    __syncthreads();
    int nd = 0;
    if (t < 124) {
        unsigned m[4] = {0u, 0u, 0u, 0u};
        for (int s = 0; s < NODES; ++s) {
            unsigned c = mcnt[t * NODES + s] + (s == t ? 1u : 0u);   // self loop
            if (c) {
                m[s >> 5] |= 1u << (s & 31);
                if (c > 1u && nd < 8) { locs[t][nd] = (s << 8) | (int)c; nd++; }
            }
        }
        uint4 mm; mm.x = m[0]; mm.y = m[1]; mm.z = m[2]; mm.w = m[3];
        *(uint4*)&gmask[(size_t)(g * NODES + t) * 4] = mm;
        cnt[t] = nd;
    } else if (t < 128) cnt[t] = 0;
    __syncthreads();
    if (t < 128) pref[t] = cnt[t];
    __syncthreads();
    for (int off = 1; off < 128; off <<= 1) {
        int v = (t >= off && t < 128) ? pref[t - off] : 0;
        __syncthreads();
        if (t < 128) pref[t] += v;
        __syncthreads();
    }
    if (t < 124) {
        int off = pref[t] - cnt[t];
        gdst[g * 132 + t] = off < EXCAP ? off : EXCAP;
        for (int j = 0; j < nd; ++j)
            if (off + j < EXCAP) gdent[g * EXCAP + off + j] = locs[t][j];
    }
    if (t == 0) {
        int tot = pref[127];
        gdst[g * 132 + 124] = tot < EXCAP ? tot : EXCAP;
    }
}

// ---------------- W^T transpose to bf16 (once) ----------------
__global__ __launch_bounds__(256) void wtrans(const float* __restrict__ W,
                                              unsigned short* __restrict__ WT) {
    __shared__ float tile[32][33];
    int kb = blockIdx.x, jb = blockIdx.y;   // k-tile (124), j-tile (4)
    int t = threadIdx.x;
    int tr = t >> 5, tc = t & 31;
    for (int r = tr; r < 32; r += 8) {
        int k = kb * 32 + r, j = jb * 32 + tc;
        tile[r][tc] = (j < 124) ? W[k * 124 + j] : 0.f;
    }
    __syncthreads();
    for (int r = tr; r < 32; r += 8) {
        int j = jb * 32 + r, k = kb * 32 + tc;
        WT[(size_t)j * NC + k] = f2bf(tile[tc][r]);
    }
}

// ---------------- fused per-graph layer kernel (+BN/relu/pool of prev layer) ---------
#define HS 136   // h plane row stride in shorts
#define TS 136   // hTall row stride
#define XS 40    // x / WT staging stride in shorts
#define ABS 136  // attB stride
#define PWS 40   // per-wave P slot row stride (shorts)

__global__ __launch_bounds__(1024, 1) void conv_graph(
    const float* __restrict__ xin, const float* __restrict__ W,
    const float* __restrict__ attl, const float* __restrict__ attr,
    const float* __restrict__ bias,
    const unsigned* __restrict__ gmask, const int* __restrict__ gdst,
    const int* __restrict__ gdent,
    const float* __restrict__ bnprev, const float* __restrict__ gprev,
    const float* __restrict__ bprev, float* __restrict__ feat, int lprev,
    float* __restrict__ y, float* __restrict__ bnacc) {

    __shared__ short hbh[128 * HS];        // h bf16 hi plane [node][ch]
    __shared__ short hbl[128 * HS];        // h bf16 lo plane
    __shared__ short hTall[128 * TS];      // full h^T hi [ch][node]; WT overlay early
    __shared__ short pwbuf[16 * 1280];     // per-wave 2xP slot; x overlay; exch overlay
    __shared__ short attBuf[16 * ABS];     // att_l/att_r B matrix
    __shared__ float ALs[4][128], ARs[4][128];
    __shared__ unsigned mask[128][4];
    __shared__ unsigned short dupst[136];
    __shared__ unsigned dupent[EXCAP];
    __shared__ float bias_s[32];
    __shared__ float bsum[8][32], bsq[8][32];
    __shared__ float pmean[32];
    __shared__ int pmax[32];

    int g = blockIdx.x, t = threadIdx.x, base = g * NODES;
    short* xh  = pwbuf;                   // [128][XS]
    short* xl  = pwbuf + 5120;
    short* WTh = hTall;                   // [128][XS]
    short* WTl = hTall + 5120;

    if (t < 32) { pmean[t] = 0.f; pmax[t] = 0; }
    __syncthreads();

    // ---- phase 1: stage (x with fused BN+relu+pool of prev layer when lprev>=0) ----
    {
        const float4* xsrc = (const float4*)(xin + (size_t)base * CC);
        for (int i = t; i < 992; i += 1024) {       // 124*32/4
            float4 v = xsrc[i];
            int n = i >> 3, c4 = i & 7;
            if (lprev >= 0) {
                float vv[4] = {v.x, v.y, v.z, v.w};
#pragma unroll
                for (int q = 0; q < 4; ++q) {
                    int c = c4 * 4 + q;
                    float mu = bnprev[c] * (1.f / NN);
                    float var = bnprev[32 + c] * (1.f / NN) - mu * mu;
                    float sc = rsqrtf(var + 1e-5f) * gprev[c];
                    float xv = (vv[q] - mu) * sc + bprev[c];
                    xv = fmaxf(xv, 0.f);
                    vv[q] = xv;
                    atomicAdd(&pmean[c], xv);
                    atomicMax(&pmax[c], __float_as_int(xv));
                }
                v.x = vv[0]; v.y = vv[1]; v.z = vv[2]; v.w = vv[3];
            }
            unsigned short h0 = f2bf(v.x), h1 = f2bf(v.y), h2 = f2bf(v.z), h3 = f2bf(v.w);
            unsigned short l0 = f2bf(v.x - bf2f(h0)), l1 = f2bf(v.y - bf2f(h1));
            unsigned short l2 = f2bf(v.z - bf2f(h2)), l3 = f2bf(v.w - bf2f(h3));
            uint2 ph; ph.x = ((unsigned)h1 << 16) | h0; ph.y = ((unsigned)h3 << 16) | h2;
            uint2 pl; pl.x = ((unsigned)l1 << 16) | l0; pl.y = ((unsigned)l3 << 16) | l2;
            *(uint2*)&xh[n * XS + c4 * 4] = ph;
            *(uint2*)&xl[n * XS + c4 * 4] = pl;
        }
        if (t < 4 * XS) { xh[124 * XS + t] = 0; xl[124 * XS + t] = 0; }
    }
    {
        int hc = t & 127, mq = t >> 7, ks = mq * 4;
        unsigned short hh4[4], ll4[4];
#pragma unroll
        for (int q = 0; q < 4; ++q) {
            float w = W[(ks + q) * HC + hc];
            hh4[q] = f2bf(w);
            ll4[q] = f2bf(w - bf2f(hh4[q]));
        }
        uint2 ph; ph.x = ((unsigned)hh4[1] << 16) | hh4[0]; ph.y = ((unsigned)hh4[3] << 16) | hh4[2];
        uint2 pl; pl.x = ((unsigned)ll4[1] << 16) | ll4[0]; pl.y = ((unsigned)ll4[3] << 16) | ll4[2];
        *(uint2*)&WTh[hc * XS + ks] = ph;
        *(uint2*)&WTl[hc * XS + ks] = pl;
    }
    for (int i = t; i < 2048; i += 1024) {
        int n = i >> 7, k = i & 127;
        float v = 0.f;
        int hidx = n & 3;
        if (n < 8 && (k >> 5) == hidx)
            v = (n < 4) ? attl[hidx * 32 + (k & 31)] : attr[hidx * 32 + (k & 31)];
        attBuf[n * ABS + k] = (short)f2bf(v);
    }
    if (t < CC) bias_s[t] = bias[t];
    if (t < 128) {
        if (t < 124) {
            uint4 m = *(const uint4*)&gmask[(size_t)(base + t) * 4];
            mask[t][0] = m.x; mask[t][1] = m.y; mask[t][2] = m.z; mask[t][3] = m.w;
        } else { mask[t][0] = 0u; mask[t][1] = 0u; mask[t][2] = 0u; mask[t][3] = 0u; }
    }
    if (t < 136) dupst[t] = (unsigned short)gdst[g * 132 + (t < 124 ? t : 124)];
    if (t >= 832 && t < 832 + EXCAP) dupent[t - 832] = (unsigned)gdent[g * EXCAP + (t - 832)];
    __syncthreads();

    // feat pool write for previous layer (runs concurrent with phase 2)
    if (lprev >= 0 && t < 32) {
        float* fp = feat + g * FEAT_DIM + NODES + lprev * 64;
        fp[t] = pmean[t] * (1.f / NODES);
        fp[32 + t] = __int_as_float(pmax[t]);
    }

    int wv = t >> 6, l = t & 63;
    int l15 = l & 15, l4 = l >> 4;

    // ---- phase 2: H = x@W via split MFMA ----
#pragma unroll
    for (int j = 0; j < 4; ++j) {
        int idx = wv * 4 + j;
        int tr = idx >> 3, tc = idx & 7;
        bf16x8 ah = *(bf16x8*)&xh[(tr * 16 + l15) * XS + l4 * 8];
        bf16x8 al_ = *(bf16x8*)&xl[(tr * 16 + l15) * XS + l4 * 8];
        bf16x8 bh = *(bf16x8*)&WTh[(tc * 16 + l15) * XS + l4 * 8];
        bf16x8 bl_ = *(bf16x8*)&WTl[(tc * 16 + l15) * XS + l4 * 8];
        f32x4 z = {0.f, 0.f, 0.f, 0.f};
        f32x4 c0 = __builtin_amdgcn_mfma_f32_16x16x32_bf16(ah, bh, z, 0, 0, 0);
        f32x4 c1 = __builtin_amdgcn_mfma_f32_16x16x32_bf16(ah, bl_, z, 0, 0, 0);
        f32x4 c2 = __builtin_amdgcn_mfma_f32_16x16x32_bf16(al_, bh, z, 0, 0, 0);
        f32x4 c = (c0 + c1) + c2;
        int hc = tc * 16 + l15;
#pragma unroll
        for (int r = 0; r < 4; ++r) {
            int n = tr * 16 + l4 * 4 + r;
            float s = c[r];
            unsigned short hi = f2bf(s);
            hbh[n * HS + hc] = (short)hi;
            hbl[n * HS + hc] = (short)f2bf(s - bf2f(hi));
        }
    }
    __syncthreads();

    // ---- phase 3: AL/AR via MFMA || hTall transpose ----
    if (wv < 8) {
        f32x4 c = {0.f, 0.f, 0.f, 0.f};
#pragma unroll
        for (int kb = 0; kb < 4; ++kb) {
            bf16x8 a = *(bf16x8*)&hbh[(wv * 16 + l15) * HS + kb * 32 + l4 * 8];
            bf16x8 b = *(bf16x8*)&attBuf[l15 * ABS + kb * 32 + l4 * 8];
            c = __builtin_amdgcn_mfma_f32_16x16x32_bf16(a, b, c, 0, 0, 0);
        }
        if (l15 < 8) {
#pragma unroll
            for (int r = 0; r < 4; ++r) {
                int n = wv * 16 + l4 * 4 + r;
                if (l15 < 4) ALs[l15][n] = c[r];
                else         ARs[l15 - 4][n] = c[r];
            }
        }
    }
#pragma unroll
    for (int hh2 = 0; hh2 < 4; ++hh2) {
        int k = t & 31, n4 = t >> 5;
        unsigned short r4[4];
#pragma unroll
        for (int r = 0; r < 4; ++r)
            r4[r] = (unsigned short)hbh[(n4 * 4 + r) * HS + hh2 * 32 + k];
        uint2 pk;
        pk.x = ((unsigned)r4[1] << 16) | r4[0];
        pk.y = ((unsigned)r4[3] << 16) | r4[2];
        *(uint2*)&hTall[(hh2 * 32 + k) * TS + n4 * 4] = pk;
    }
    __syncthreads();

    // ---- phase 4: barrier-free pipelined attention body (sequential heads) ----
    int DJ = wv >> 1;
    float accA[4] = {0.f, 0.f, 0.f, 0.f};
    float accB[4] = {0.f, 0.f, 0.f, 0.f};
    {
        int hh0 = (wv & 1) * 2;
        short* pwb = pwbuf + wv * 1280;    // 2 slots x 640 shorts
        int dst = DJ * 16 + l15;
        uint4 mrow = *(uint4*)&mask[dst][0];
        unsigned mwords[4] = {mrow.x, mrow.y, mrow.z, mrow.w};
        unsigned cntp[8];
#pragma unroll
        for (int SI = 0; SI < 8; ++SI) {
            unsigned mw = (mwords[SI >> 1] >> ((SI & 1) * 16 + l4 * 4)) & 0xFu;
            cntp[SI] = (mw & 1u) | ((mw & 2u) << 7) | ((mw & 4u) << 14) | ((mw & 8u) << 21);
        }
        {
            int s0 = dupst[dst], s1 = dupst[dst + 1];
            for (int e = s0; e < s1; ++e) {
                unsigned ent = dupent[e];
                unsigned src = (ent >> 8) & 255u;
                unsigned SI = src >> 4;
                unsigned r = (src & 15u) - (unsigned)(l4 * 4);
                if (r < 4u) {
                    unsigned sh = 8u * r;
                    cntp[SI] = (cntp[SI] & ~(255u << sh)) | ((ent & 255u) << sh);
                }
            }
        }

#define GRAM(kb, slot) { \
    _Pragma("unroll") \
    for (int s2 = 0; s2 < 2; ++s2) { \
        int SI = (kb) * 2 + s2; \
        int ao = (SI * 16 + l15) * HS + hh * 32 + l4 * 8; \
        bf16x8 ah = *(bf16x8*)&hbh[ao]; \
        bf16x8 al_ = *(bf16x8*)&hbl[ao]; \
        f32x4 z2 = {0.f, 0.f, 0.f, 0.f}; \
        f32x4 c0 = __builtin_amdgcn_mfma_f32_16x16x32_bf16(ah, gb, z2, 0, 0, 0); \
        f32x4 c1 = __builtin_amdgcn_mfma_f32_16x16x32_bf16(ah, gl, z2, 0, 0, 0); \
        f32x4 c2 = __builtin_amdgcn_mfma_f32_16x16x32_bf16(al_, gb, z2, 0, 0, 0); \
        f32x4 c = (c0 + c1) + c2; \
        int src0 = SI * 16 + l4 * 4; \
        float4 al4 = *(float4*)&ALs[hh][src0]; \
        unsigned cp = cntp[SI]; \
        float pv[4]; \
        _Pragma("unroll") \
        for (int r = 0; r < 4; ++r) { \
            float e2 = __builtin_amdgcn_exp2f(-LOG2E * c[r]); \
            float sig = __builtin_amdgcn_rcpf(1.f + e2); \
            float a2 = (((const float*)&al4)[r] + ar) * sig; \
            float m = fmaxf(a2 * LOG2E, a2 * LOG2E5); \
            float cr = (float)((cp >> (8 * r)) & 255u); \
            pv[r] = __builtin_amdgcn_exp2f(m) * cr; \
        } \
        sden += (pv[0] + pv[1]) + (pv[2] + pv[3]); \
        unsigned w0_, w1_; \
        asm("v_cvt_pk_bf16_f32 %0, %1, %2" : "=v"(w0_) : "v"(pv[0]), "v"(pv[1])); \
        asm("v_cvt_pk_bf16_f32 %0, %1, %2" : "=v"(w1_) : "v"(pv[2]), "v"(pv[3])); \
        uint2 pk_; pk_.x = w0_; pk_.y = w1_; \
        *(uint2*)&pwb[(slot) * 640 + l15 * PWS + s2 * 16 + l4 * 4] = pk_; \
    } }

#define PVOP(kb, slot) { \
    bf16x8 a = *(bf16x8*)&pwb[(slot) * 640 + l15 * PWS + l4 * 8]; \
    bf16x8 b0 = *(bf16x8*)&hTall[(hh * 32 + l15) * TS + (kb) * 32 + l4 * 8]; \
    bf16x8 b1 = *(bf16x8*)&hTall[(hh * 32 + 16 + l15) * TS + (kb) * 32 + l4 * 8]; \
    num0 = __builtin_amdgcn_mfma_f32_16x16x32_bf16(a, b0, num0, 0, 0, 0); \
    num1 = __builtin_amdgcn_mfma_f32_16x16x32_bf16(a, b1, num1, 0, 0, 0); }

#pragma unroll
        for (int jj = 0; jj < 2; ++jj) {
            int hh = hh0 + jj;
            bf16x8 gb = *(bf16x8*)&hbh[dst * HS + hh * 32 + l4 * 8];
            bf16x8 gl = *(bf16x8*)&hbl[dst * HS + hh * 32 + l4 * 8];
            float ar = ARs[hh][dst];
            float sden = 0.f;
            f32x4 num0 = {0.f, 0.f, 0.f, 0.f};
            f32x4 num1 = {0.f, 0.f, 0.f, 0.f};
            GRAM(0, 0);
            GRAM(1, 1); PVOP(0, 0);
            GRAM(2, 0); PVOP(1, 1);
            GRAM(3, 1); PVOP(2, 0);
            PVOP(3, 1);
            sden += __shfl_xor(sden, 16, 64);
            sden += __shfl_xor(sden, 32, 64);
#pragma unroll
            for (int r = 0; r < 4; ++r) {
                float dn = __shfl(sden, l4 * 4 + r, 64) + 1e-16f;
                accA[r] += ((float*)&num0)[r] / dn;
                accB[r] += ((float*)&num1)[r] / dn;
            }
        }
#undef GRAM
#undef PVOP
    }
    __syncthreads();

    // ---- phase 5: pair1 -> exchange ----
    float* exch = (float*)pwbuf;
    if (wv & 1) {
#pragma unroll
        for (int r = 0; r < 4; ++r) {
            exch[DJ * 512 + l15 * 16 + l4 * 4 + r] = accA[r];
            exch[DJ * 512 + 256 + l15 * 16 + l4 * 4 + r] = accB[r];
        }
    }
    __syncthreads();

    // ---- phase 6: pair0 combine + y store + BN partials ----
    if (!(wv & 1)) {
        float sA = 0.f, qA = 0.f, sB = 0.f, qB = 0.f;
#pragma unroll
        for (int r = 0; r < 4; ++r) {
            int n = DJ * 16 + l4 * 4 + r;
            float a = accA[r] + exch[DJ * 512 + l15 * 16 + l4 * 4 + r];
            float b = accB[r] + exch[DJ * 512 + 256 + l15 * 16 + l4 * 4 + r];
            a = 0.25f * a + bias_s[l15];
            b = 0.25f * b + bias_s[16 + l15];
            if (n < NODES) {
                y[(size_t)(base + n) * CC + l15] = a;
                y[(size_t)(base + n) * CC + 16 + l15] = b;
                sA += a; qA += a * a; sB += b; qB += b * b;
            }
        }
        sA += __shfl_xor(sA, 16, 64); sA += __shfl_xor(sA, 32, 64);
        qA += __shfl_xor(qA, 16, 64); qA += __shfl_xor(qA, 32, 64);
        sB += __shfl_xor(sB, 16, 64); sB += __shfl_xor(sB, 32, 64);
        qB += __shfl_xor(qB, 16, 64); qB += __shfl_xor(qB, 32, 64);
        if (l < 16) {
            bsum[DJ][l15] = sA; bsum[DJ][16 + l15] = sB;
            bsq[DJ][l15] = qA;  bsq[DJ][16 + l15] = qB;
        }
    }
    __syncthreads();
    if (t < CC) {
        float S = 0.f, Q = 0.f;
#pragma unroll
        for (int w = 0; w < 8; ++w) { S += bsum[w][t]; Q += bsq[w][t]; }
        atomicAdd(&bnacc[t], S);
        atomicAdd(&bnacc[CC + t], Q);
    }
}

// BN + relu -> xbf (bf16) ; per-graph mean/max pool -> feat (last layer only)
__global__ void bn_relu_pool(const float* __restrict__ y, const float* __restrict__ acc,
                             const float* __restrict__ gamma, const float* __restrict__ beta,
                             unsigned short* __restrict__ xbf, float* __restrict__ feat, int l) {
    int g = blockIdx.x;
    int t = threadIdx.x;          // 128
    int c = t & 31, r0 = t >> 5;
    float mu = acc[c] * (1.f / NN);
    float var = acc[32 + c] * (1.f / NN) - mu * mu;
    float sc = rsqrtf(var + 1e-5f) * gamma[c];
    float bt = beta[c];
    float s = 0.f, mx = -INFINITY;
    for (int r = r0; r < NODES; r += 4) {
        int i = (g * NODES + r) * CC + c;
        float v = (y[i] - mu) * sc + bt;
        v = fmaxf(v, 0.f);
        xbf[i] = f2bf(v);
        s += v; mx = fmaxf(mx, v);
    }
    __shared__ float ls[128], lm[128];
    ls[t] = s; lm[t] = mx;
    __syncthreads();
    if (t < 32) {
        float S = ls[t] + ls[32 + t] + ls[64 + t] + ls[96 + t];
        float M = fmaxf(fmaxf(lm[t], lm[32 + t]), fmaxf(lm[64 + t], lm[96 + t]));
        float* fp = feat + g * FEAT_DIM + NODES + l * 64;
        fp[t] = S * (1.f / NODES);
        fp[32 + t] = M;
    }
}

// ---------------- classifier head ----------------
#define L1_KS 4
#define L1_KC 992    // NC / 4 = 31 K-steps of 32
#define XP 1000      // Xs row stride in shorts
__global__ __launch_bounds__(512) void lin1_mfma(const unsigned short* __restrict__ Xb,
                                                 const unsigned short* __restrict__ WT,
                                                 float* __restrict__ part) {
    __shared__ unsigned short Xs[16 * XP];   // 32 KB
    int mt = blockIdx.x >> 2, kp = blockIdx.x & 3;
    int t = threadIdx.x;
    int wv = t >> 6, l = t & 63, l15 = l & 15, l4 = l >> 4;
    int M0 = mt * 16, k0 = kp * L1_KC;
    for (int i = t; i < 16 * 124; i += 512) {
        int r = i / 124, c = i - r * 124;
        *(uint4*)&Xs[r * XP + c * 8] = *(const uint4*)&Xb[(size_t)(M0 + r) * NC + k0 + c * 8];
    }
    __syncthreads();
    int N0 = wv * 16;
    f32x4 acc = {0.f, 0.f, 0.f, 0.f};
#pragma unroll 4
    for (int kk = 0; kk < 31; ++kk) {
        bf16x8 a = *(bf16x8*)&Xs[l15 * XP + kk * 32 + l4 * 8];
        bf16x8 b = *(const bf16x8*)&WT[(size_t)(N0 + l15) * NC + k0 + kk * 32 + l4 * 8];
        acc = __builtin_amdgcn_mfma_f32_16x16x32_bf16(a, b, acc, 0, 0, 0);
    }
    if (N0 + l15 < 124) {
#pragma unroll
        for (int r = 0; r < 4; ++r)
            part[(size_t)kp * NB * 124 + (M0 + l4 * 4 + r) * 124 + N0 + l15] = acc[r];
    }
}

__global__ void lin1_reduce(const float* __restrict__ part, const float* __restrict__ b,
                            float* __restrict__ out1) {
    int i = blockIdx.x * blockDim.x + threadIdx.x;
    if (i >= NB * 124) return;
    int j = i % 124;
    float s = b[j];
#pragma unroll
    for (int ks = 0; ks < L1_KS; ++ks) s += part[ks * NB * 124 + i];
    out1[i] = s;
}

__global__ void bn1_relu(const float* __restrict__ out1, const float* __restrict__ gamma,
                         const float* __restrict__ beta, float* __restrict__ feat) {
    __shared__ float ps[4][124], pq[4][124], smu[124], ssc[124], sbt[124];
    int t = threadIdx.x;
    int c = t & 127, seg = t >> 7;
    float s = 0.f, q = 0.f;
    if (c < 124) {
        for (int b = seg * 64; b < seg * 64 + 64; ++b) {
            float v = out1[b * 124 + c]; s += v; q += v * v;
        }
        ps[seg][c] = s; pq[seg][c] = q;
    }
    __syncthreads();
    if (t < 124) {
        float S = ps[0][t] + ps[1][t] + ps[2][t] + ps[3][t];
        float Q = pq[0][t] + pq[1][t] + pq[2][t] + pq[3][t];
        float mu = S * (1.f / NB);
        float var = Q * (1.f / NB) - mu * mu;
        smu[t] = mu; ssc[t] = rsqrtf(var + 1e-5f) * gamma[t]; sbt[t] = beta[t];
    }
    __syncthreads();
    if (c < 124) {
        for (int b = seg * 64; b < seg * 64 + 64; ++b) {
            float v = (out1[b * 124 + c] - smu[c]) * ssc[c] + sbt[c];
            feat[b * FEAT_DIM + c] = fmaxf(v, 0.f);
        }
    }
}

__global__ void lin2_k(const float* __restrict__ feat, const float* __restrict__ W,
                       const float* __restrict__ b, float* __restrict__ out) {
    __shared__ float psum[8][40];
    int g = blockIdx.x;
    int t = threadIdx.x;
    int j = t % 40, u = t / 40;
    if (u < 8) {
        int k0 = u * 40, k1 = (u == 7) ? FEAT_DIM : k0 + 40;
        float s = 0.f;
        for (int k = k0; k < k1; ++k) s += feat[g * FEAT_DIM + k] * W[k * NCLS + j];
        psum[u][j] = s;
    }
    __syncthreads();
    if (t < NCLS) {
        float s = b[t];
#pragma unroll
        for (int u2 = 0; u2 < 8; ++u2) s += psum[u2][t];
        out[g * NCLS + t] = s;
    }
}

extern "C" void kernel_launch(void* const* d_in, const int* in_sizes, int n_in,
                              void* d_out, int out_size, void* d_ws, size_t ws_size,
                              hipStream_t stream) {
    const float* x      = (const float*)d_in[0];
    const int*   ei     = (const int*)d_in[1];
    const float* conv_W = (const float*)d_in[3];
    const float* att_l  = (const float*)d_in[4];
    const float* att_r  = (const float*)d_in[5];
    const float* conv_b = (const float*)d_in[6];
    const float* bn_g   = (const float*)d_in[7];
    const float* bn_b   = (const float*)d_in[8];
    const float* lin1_W = (const float*)d_in[9];
    const float* lin1_b = (const float*)d_in[10];
    const float* bn1_g  = (const float*)d_in[11];
    const float* bn1_b  = (const float*)d_in[12];
    const float* lin2_W = (const float*)d_in[13];
    const float* lin2_b = (const float*)d_in[14];

    float* ws = (float*)d_ws;
    float* y = ws;                                           // NN*32 fp32
    unsigned short* xbf = (unsigned short*)(y + (size_t)NN * CC);   // NN*32 bf16
    float* bnacc = (float*)(xbf + (size_t)NN * CC);          // 192
    float* feat  = bnacc + 192;                              // NB*316
    float* out1  = feat + NB * FEAT_DIM;                     // NB*124
    float* part  = out1 + NB * 124;                          // 4*NB*124
    unsigned short* WT = (unsigned short*)(part + L1_KS * NB * 124);  // 128*3968 bf16
    unsigned* gmask = (unsigned*)(WT + (size_t)128 * NC);    // NN*4
    int* gdst  = (int*)(gmask + (size_t)NN * 4);             // NB*132
    int* gdent = gdst + NB * 132;                            // NB*EXCAP

    mask_build<<<NB, 256, 0, stream>>>(ei, gmask, gdst, gdent, bnacc);
    wtrans<<<dim3(NC / 32, 4), 256, 0, stream>>>(lin1_W, WT);

    const float* xin = x;
    for (int l = 0; l < 3; ++l) {
        const float* bnprev = (l == 0) ? nullptr : bnacc + (l - 1) * 64;
        const float* gprev  = (l == 0) ? bn_g : bn_g + (l - 1) * CC;
        const float* bprev  = (l == 0) ? bn_b : bn_b + (l - 1) * CC;
        conv_graph<<<NB, 1024, 0, stream>>>(xin, conv_W + l * CC * HC,
                                            att_l + l * HC, att_r + l * HC,
                                            conv_b + l * CC, gmask, gdst, gdent,
                                            bnprev, gprev, bprev, feat, l - 1,
                                            y, bnacc + l * 64);
        xin = y;
    }

    bn_relu_pool<<<NB, 128, 0, stream>>>(y, bnacc + 128, bn_g + 2 * CC, bn_b + 2 * CC,
                                         xbf, feat, 2);
    lin1_mfma<<<64, 512, 0, stream>>>(xbf, WT, part);
    lin1_reduce<<<(NB * 124 + 255) / 256, 256, 0, stream>>>(part, lin1_b, out1);
    bn1_relu<<<1, 512, 0, stream>>>(out1, bn1_g, bn1_b, feat);
    lin2_k<<<NB, 320, 0, stream>>>(feat, lin2_W, lin2_b, (float*)d_out);
}

// Round 18
// 141.549 us; speedup vs baseline: 1.0738x; 1.0216x over previous
//
#include <hip/hip_runtime.h>
#include <math.h>

#define NN 31744        // total nodes B*NODES
#define NE 507904       // input edges (no self loops)
#define EP 1984         // edges per graph
#define NODES 124
#define NB 256          // graphs
#define CC 32           // channels
#define HC 128          // H*C
#define FEAT_DIM 316
#define NCLS 40
#define NC 3968         // NODES*CC
#define EXCAP 192

typedef __attribute__((ext_vector_type(8))) short bf16x8;
typedef __attribute__((ext_vector_type(4))) float f32x4;

#define LOG2E  1.44269504f
#define LOG2E5 0.28853901f   // 0.2 * log2(e)

__device__ __forceinline__ unsigned short f2bf(float f) {
    unsigned u = __float_as_uint(f);
    u = u + 0x7FFFu + ((u >> 16) & 1u);      // RNE
    return (unsigned short)(u >> 16);
}
__device__ __forceinline__ float bf2f(unsigned short s) {
    return __uint_as_float(((unsigned)s) << 16);
}

// ---------------- per-graph mask + duplicate-edge build (layer-invariant) -------------
__global__ __launch_bounds__(256) void mask_build(const int* __restrict__ ei,
                                                  unsigned* __restrict__ gmask,
                                                  int* __restrict__ gdst,
                                                  int* __restrict__ gdent,
                                                  float* __restrict__ bnacc) {
    __shared__ unsigned mcnt[NODES * NODES];   // 61.5 KB
    __shared__ int cnt[128], pref[128];
    __shared__ int locs[124][8];
    int g = blockIdx.x, t = threadIdx.x;
    if (g == 0 && t < 192) bnacc[t] = 0.f;     // zero all 3 layers' BN accumulators
    for (int i = t; i < NODES * NODES; i += 256) mcnt[i] = 0u;
    __syncthreads();
    for (int e = t; e < EP; e += 256) {
        int s = ei[g * EP + e] - g * NODES;
        int d = ei[NE + g * EP + e] - g * NODES;
        atomicAdd(&mcnt[d * NODES + s], 1u);
    }
    __syncthreads();
    int nd = 0;
    if (t < 124) {
        unsigned m[4] = {0u, 0u, 0u, 0u};
        for (int s = 0; s < NODES; ++s) {
            unsigned c = mcnt[t * NODES + s] + (s == t ? 1u : 0u);   // self loop
            if (c) {
                m[s >> 5] |= 1u << (s & 31);
                if (c > 1u && nd < 8) { locs[t][nd] = (s << 8) | (int)c; nd++; }
            }
        }
        uint4 mm; mm.x = m[0]; mm.y = m[1]; mm.z = m[2]; mm.w = m[3];
        *(uint4*)&gmask[(size_t)(g * NODES + t) * 4] = mm;
        cnt[t] = nd;
    } else if (t < 128) cnt[t] = 0;
    __syncthreads();
    if (t < 128) pref[t] = cnt[t];
    __syncthreads();
    for (int off = 1; off < 128; off <<= 1) {
        int v = (t >= off && t < 128) ? pref[t - off] : 0;
        __syncthreads();
        if (t < 128) pref[t] += v;
        __syncthreads();
    }
    if (t < 124) {
        int off = pref[t] - cnt[t];
        gdst[g * 132 + t] = off < EXCAP ? off : EXCAP;
        for (int j = 0; j < nd; ++j)
            if (off + j < EXCAP) gdent[g * EXCAP + off + j] = locs[t][j];
    }
    if (t == 0) {
        int tot = pref[127];
        gdst[g * 132 + 124] = tot < EXCAP ? tot : EXCAP;
    }
}

// ---------------- W^T transpose to bf16 (once) ----------------
__global__ __launch_bounds__(256) void wtrans(const float* __restrict__ W,
                                              unsigned short* __restrict__ WT) {
    __shared__ float tile[32][33];
    int kb = blockIdx.x, jb = blockIdx.y;   // k-tile (124), j-tile (4)
    int t = threadIdx.x;
    int tr = t >> 5, tc = t & 31;
    for (int r = tr; r < 32; r += 8) {
        int k = kb * 32 + r, j = jb * 32 + tc;
        tile[r][tc] = (j < 124) ? W[k * 124 + j] : 0.f;
    }
    __syncthreads();
    for (int r = tr; r < 32; r += 8) {
        int j = jb * 32 + r, k = kb * 32 + tc;
        WT[(size_t)j * NC + k] = f2bf(tile[tc][r]);
    }
}

// ---------------- fused per-graph layer kernel (+BN/relu/pool of prev layer) ---------
#define HS 136   // h plane row stride in shorts
#define TS 136   // hTall row stride
#define XS 40    // x / WT staging stride in shorts
#define ABS 136  // attB stride
#define PWS 40   // per-wave P slot row stride (shorts)

__global__ __launch_bounds__(1024, 1) void conv_graph(
    const float* __restrict__ xin, const float* __restrict__ W,
    const float* __restrict__ attl, const float* __restrict__ attr,
    const float* __restrict__ bias,
    const unsigned* __restrict__ gmask, const int* __restrict__ gdst,
    const int* __restrict__ gdent,
    const float* __restrict__ bnprev, const float* __restrict__ gprev,
    const float* __restrict__ bprev, float* __restrict__ feat, int lprev,
    float* __restrict__ y, float* __restrict__ bnacc) {

    __shared__ short hbh[128 * HS];        // h bf16 hi plane [node][ch]
    __shared__ short hbl[128 * HS];        // h bf16 lo plane
    __shared__ short hTall[128 * TS];      // full h^T hi [ch][node]; WT overlay early
    __shared__ short pwbuf[16 * 1280];     // per-wave 2xP slot; x overlay; exch overlay
    __shared__ short attBuf[16 * ABS];     // att_l/att_r B matrix
    __shared__ float ALs[4][128], ARs[4][128];
    __shared__ unsigned mask[128][4];
    __shared__ unsigned short dupst[136];
    __shared__ unsigned dupent[EXCAP];
    __shared__ float bias_s[32];
    __shared__ float bsum[8][32], bsq[8][32];
    __shared__ float pmean[32];
    __shared__ int pmax[32];

    int g = blockIdx.x, t = threadIdx.x, base = g * NODES;
    short* xh  = pwbuf;                   // [128][XS]
    short* xl  = pwbuf + 5120;
    short* WTh = hTall;                   // [128][XS]
    short* WTl = hTall + 5120;

    if (t < 32) { pmean[t] = 0.f; pmax[t] = 0; }
    __syncthreads();

    // ---- phase 1: stage (x with fused BN+relu+pool of prev layer when lprev>=0) ----
    {
        const float4* xsrc = (const float4*)(xin + (size_t)base * CC);
        for (int i = t; i < 992; i += 1024) {       // 124*32/4
            float4 v = xsrc[i];
            int n = i >> 3, c4 = i & 7;
            if (lprev >= 0) {
                float vv[4] = {v.x, v.y, v.z, v.w};
#pragma unroll
                for (int q = 0; q < 4; ++q) {
                    int c = c4 * 4 + q;
                    float mu = bnprev[c] * (1.f / NN);
                    float var = bnprev[32 + c] * (1.f / NN) - mu * mu;
                    float sc = rsqrtf(var + 1e-5f) * gprev[c];
                    float xv = (vv[q] - mu) * sc + bprev[c];
                    xv = fmaxf(xv, 0.f);
                    vv[q] = xv;
                    atomicAdd(&pmean[c], xv);
                    atomicMax(&pmax[c], __float_as_int(xv));
                }
                v.x = vv[0]; v.y = vv[1]; v.z = vv[2]; v.w = vv[3];
            }
            unsigned short h0 = f2bf(v.x), h1 = f2bf(v.y), h2 = f2bf(v.z), h3 = f2bf(v.w);
            unsigned short l0 = f2bf(v.x - bf2f(h0)), l1 = f2bf(v.y - bf2f(h1));
            unsigned short l2 = f2bf(v.z - bf2f(h2)), l3 = f2bf(v.w - bf2f(h3));
            uint2 ph; ph.x = ((unsigned)h1 << 16) | h0; ph.y = ((unsigned)h3 << 16) | h2;
            uint2 pl; pl.x = ((unsigned)l1 << 16) | l0; pl.y = ((unsigned)l3 << 16) | l2;
            *(uint2*)&xh[n * XS + c4 * 4] = ph;
            *(uint2*)&xl[n * XS + c4 * 4] = pl;
        }
        if (t < 4 * XS) { xh[124 * XS + t] = 0; xl[124 * XS + t] = 0; }
    }
    {
        int hc = t & 127, mq = t >> 7, ks = mq * 4;
        unsigned short hh4[4], ll4[4];
#pragma unroll
        for (int q = 0; q < 4; ++q) {
            float w = W[(ks + q) * HC + hc];
            hh4[q] = f2bf(w);
            ll4[q] = f2bf(w - bf2f(hh4[q]));
        }
        uint2 ph; ph.x = ((unsigned)hh4[1] << 16) | hh4[0]; ph.y = ((unsigned)hh4[3] << 16) | hh4[2];
        uint2 pl; pl.x = ((unsigned)ll4[1] << 16) | ll4[0]; pl.y = ((unsigned)ll4[3] << 16) | ll4[2];
        *(uint2*)&WTh[hc * XS + ks] = ph;
        *(uint2*)&WTl[hc * XS + ks] = pl;
    }
    for (int i = t; i < 2048; i += 1024) {
        int n = i >> 7, k = i & 127;
        float v = 0.f;
        int hidx = n & 3;
        if (n < 8 && (k >> 5) == hidx)
            v = (n < 4) ? attl[hidx * 32 + (k & 31)] : attr[hidx * 32 + (k & 31)];
        attBuf[n * ABS + k] = (short)f2bf(v);
    }
    if (t < CC) bias_s[t] = bias[t];
    if (t < 128) {
        if (t < 124) {
            uint4 m = *(const uint4*)&gmask[(size_t)(base + t) * 4];
            mask[t][0] = m.x; mask[t][1] = m.y; mask[t][2] = m.z; mask[t][3] = m.w;
        } else { mask[t][0] = 0u; mask[t][1] = 0u; mask[t][2] = 0u; mask[t][3] = 0u; }
    }
    if (t < 136) dupst[t] = (unsigned short)gdst[g * 132 + (t < 124 ? t : 124)];
    if (t >= 832 && t < 832 + EXCAP) dupent[t - 832] = (unsigned)gdent[g * EXCAP + (t - 832)];
    __syncthreads();

    // feat pool write for previous layer (runs concurrent with phase 2)
    if (lprev >= 0 && t < 32) {
        float* fp = feat + g * FEAT_DIM + NODES + lprev * 64;
        fp[t] = pmean[t] * (1.f / NODES);
        fp[32 + t] = __int_as_float(pmax[t]);
    }

    int wv = t >> 6, l = t & 63;
    int l15 = l & 15, l4 = l >> 4;

    // ---- phase 2: H = x@W via split MFMA ----
#pragma unroll
    for (int j = 0; j < 4; ++j) {
        int idx = wv * 4 + j;
        int tr = idx >> 3, tc = idx & 7;
        bf16x8 ah = *(bf16x8*)&xh[(tr * 16 + l15) * XS + l4 * 8];
        bf16x8 al_ = *(bf16x8*)&xl[(tr * 16 + l15) * XS + l4 * 8];
        bf16x8 bh = *(bf16x8*)&WTh[(tc * 16 + l15) * XS + l4 * 8];
        bf16x8 bl_ = *(bf16x8*)&WTl[(tc * 16 + l15) * XS + l4 * 8];
        f32x4 z = {0.f, 0.f, 0.f, 0.f};
        f32x4 c0 = __builtin_amdgcn_mfma_f32_16x16x32_bf16(ah, bh, z, 0, 0, 0);
        f32x4 c1 = __builtin_amdgcn_mfma_f32_16x16x32_bf16(ah, bl_, z, 0, 0, 0);
        f32x4 c2 = __builtin_amdgcn_mfma_f32_16x16x32_bf16(al_, bh, z, 0, 0, 0);
        f32x4 c = (c0 + c1) + c2;
        int hc = tc * 16 + l15;
#pragma unroll
        for (int r = 0; r < 4; ++r) {
            int n = tr * 16 + l4 * 4 + r;
            float s = c[r];
            unsigned short hi = f2bf(s);
            hbh[n * HS + hc] = (short)hi;
            hbl[n * HS + hc] = (short)f2bf(s - bf2f(hi));
        }
    }
    __syncthreads();

    // ---- phase 3: AL/AR via MFMA || hTall transpose ----
    if (wv < 8) {
        f32x4 c = {0.f, 0.f, 0.f, 0.f};
#pragma unroll
        for (int kb = 0; kb < 4; ++kb) {
            bf16x8 a = *(bf16x8*)&hbh[(wv * 16 + l15) * HS + kb * 32 + l4 * 8];
            bf16x8 b = *(bf16x8*)&attBuf[l15 * ABS + kb * 32 + l4 * 8];
            c = __builtin_amdgcn_mfma_f32_16x16x32_bf16(a, b, c, 0, 0, 0);
        }
        if (l15 < 8) {
#pragma unroll
            for (int r = 0; r < 4; ++r) {
                int n = wv * 16 + l4 * 4 + r;
                if (l15 < 4) ALs[l15][n] = c[r];
                else         ARs[l15 - 4][n] = c[r];
            }
        }
    }
#pragma unroll
    for (int hh2 = 0; hh2 < 4; ++hh2) {
        int k = t & 31, n4 = t >> 5;
        unsigned short r4[4];
#pragma unroll
        for (int r = 0; r < 4; ++r)
            r4[r] = (unsigned short)hbh[(n4 * 4 + r) * HS + hh2 * 32 + k];
        uint2 pk;
        pk.x = ((unsigned)r4[1] << 16) | r4[0];
        pk.y = ((unsigned)r4[3] << 16) | r4[2];
        *(uint2*)&hTall[(hh2 * 32 + k) * TS + n4 * 4] = pk;
    }
    __syncthreads();

    // ---- phase 4: barrier-free pipelined attention body (sequential heads) ----
    int DJ = wv >> 1;
    float accA[4] = {0.f, 0.f, 0.f, 0.f};
    float accB[4] = {0.f, 0.f, 0.f, 0.f};
    {
        int hh0 = (wv & 1) * 2;
        short* pwb = pwbuf + wv * 1280;    // 2 slots x 640 shorts
        int dst = DJ * 16 + l15;
        uint4 mrow = *(uint4*)&mask[dst][0];
        unsigned mwords[4] = {mrow.x, mrow.y, mrow.z, mrow.w};
        unsigned cntp[8];
#pragma unroll
        for (int SI = 0; SI < 8; ++SI) {
            unsigned mw = (mwords[SI >> 1] >> ((SI & 1) * 16 + l4 * 4)) & 0xFu;
            cntp[SI] = (mw & 1u) | ((mw & 2u) << 7) | ((mw & 4u) << 14) | ((mw & 8u) << 21);
        }
        {
            int s0 = dupst[dst], s1 = dupst[dst + 1];
            for (int e = s0; e < s1; ++e) {
                unsigned ent = dupent[e];
                unsigned src = (ent >> 8) & 255u;
                unsigned SI = src >> 4;
                unsigned r = (src & 15u) - (unsigned)(l4 * 4);
                if (r < 4u) {
                    unsigned sh = 8u * r;
                    cntp[SI] = (cntp[SI] & ~(255u << sh)) | ((ent & 255u) << sh);
                }
            }
        }

#define GRAM(kb, slot) { \
    _Pragma("unroll") \
    for (int s2 = 0; s2 < 2; ++s2) { \
        int SI = (kb) * 2 + s2; \
        int ao = (SI * 16 + l15) * HS + hh * 32 + l4 * 8; \
        bf16x8 ah = *(bf16x8*)&hbh[ao]; \
        bf16x8 al_ = *(bf16x8*)&hbl[ao]; \
        f32x4 z2 = {0.f, 0.f, 0.f, 0.f}; \
        f32x4 c0 = __builtin_amdgcn_mfma_f32_16x16x32_bf16(ah, gb, z2, 0, 0, 0); \
        f32x4 c1 = __builtin_amdgcn_mfma_f32_16x16x32_bf16(ah, gl, z2, 0, 0, 0); \
        f32x4 c2 = __builtin_amdgcn_mfma_f32_16x16x32_bf16(al_, gb, z2, 0, 0, 0); \
        f32x4 c = (c0 + c1) + c2; \
        int src0 = SI * 16 + l4 * 4; \
        float4 al4 = *(float4*)&ALs[hh][src0]; \
        unsigned cp = cntp[SI]; \
        float pv[4]; \
        _Pragma("unroll") \
        for (int r = 0; r < 4; ++r) { \
            float e2 = __builtin_amdgcn_exp2f(-LOG2E * c[r]); \
            float sig = __builtin_amdgcn_rcpf(1.f + e2); \
            float a2 = (((const float*)&al4)[r] + ar) * sig; \
            float m = fmaxf(a2 * LOG2E, a2 * LOG2E5); \
            float cr = (float)((cp >> (8 * r)) & 255u); \
            pv[r] = __builtin_amdgcn_exp2f(m) * cr; \
        } \
        sden += (pv[0] + pv[1]) + (pv[2] + pv[3]); \
        unsigned w0_, w1_; \
        asm("v_cvt_pk_bf16_f32 %0, %1, %2" : "=v"(w0_) : "v"(pv[0]), "v"(pv[1])); \
        asm("v_cvt_pk_bf16_f32 %0, %1, %2" : "=v"(w1_) : "v"(pv[2]), "v"(pv[3])); \
        uint2 pk_; pk_.x = w0_; pk_.y = w1_; \
        *(uint2*)&pwb[(slot) * 640 + l15 * PWS + s2 * 16 + l4 * 4] = pk_; \
    } }

#define PVOP(kb, slot) { \
    bf16x8 a = *(bf16x8*)&pwb[(slot) * 640 + l15 * PWS + l4 * 8]; \
    bf16x8 b0 = *(bf16x8*)&hTall[(hh * 32 + l15) * TS + (kb) * 32 + l4 * 8]; \
    bf16x8 b1 = *(bf16x8*)&hTall[(hh * 32 + 16 + l15) * TS + (kb) * 32 + l4 * 8]; \
    num0 = __builtin_amdgcn_mfma_f32_16x16x32_bf16(a, b0, num0, 0, 0, 0); \
    num1 = __builtin_amdgcn_mfma_f32_16x16x32_bf16(a, b1, num1, 0, 0, 0); }

#pragma unroll
        for (int jj = 0; jj < 2; ++jj) {
            int hh = hh0 + jj;
            bf16x8 gb = *(bf16x8*)&hbh[dst * HS + hh * 32 + l4 * 8];
            bf16x8 gl = *(bf16x8*)&hbl[dst * HS + hh * 32 + l4 * 8];
            float ar = ARs[hh][dst];
            float sden = 0.f;
            f32x4 num0 = {0.f, 0.f, 0.f, 0.f};
            f32x4 num1 = {0.f, 0.f, 0.f, 0.f};
            GRAM(0, 0);
            GRAM(1, 1); PVOP(0, 0);
            GRAM(2, 0); PVOP(1, 1);
            GRAM(3, 1); PVOP(2, 0);
            PVOP(3, 1);
            sden += __shfl_xor(sden, 16, 64);
            sden += __shfl_xor(sden, 32, 64);
#pragma unroll
            for (int r = 0; r < 4; ++r) {
                float dn = __shfl(sden, l4 * 4 + r, 64) + 1e-16f;
                accA[r] += ((float*)&num0)[r] / dn;
                accB[r] += ((float*)&num1)[r] / dn;
            }
        }
#undef GRAM
#undef PVOP
    }
    __syncthreads();

    // ---- phase 5: pair1 -> exchange ----
    float* exch = (float*)pwbuf;
    if (wv & 1) {
#pragma unroll
        for (int r = 0; r < 4; ++r) {
            exch[DJ * 512 + l15 * 16 + l4 * 4 + r] = accA[r];
            exch[DJ * 512 + 256 + l15 * 16 + l4 * 4 + r] = accB[r];
        }
    }
    __syncthreads();

    // ---- phase 6: pair0 combine + y store + BN partials ----
    if (!(wv & 1)) {
        float sA = 0.f, qA = 0.f, sB = 0.f, qB = 0.f;
#pragma unroll
        for (int r = 0; r < 4; ++r) {
            int n = DJ * 16 + l4 * 4 + r;
            float a = accA[r] + exch[DJ * 512 + l15 * 16 + l4 * 4 + r];
            float b = accB[r] + exch[DJ * 512 + 256 + l15 * 16 + l4 * 4 + r];
            a = 0.25f * a + bias_s[l15];
            b = 0.25f * b + bias_s[16 + l15];
            if (n < NODES) {
                y[(size_t)(base + n) * CC + l15] = a;
                y[(size_t)(base + n) * CC + 16 + l15] = b;
                sA += a; qA += a * a; sB += b; qB += b * b;
            }
        }
        sA += __shfl_xor(sA, 16, 64); sA += __shfl_xor(sA, 32, 64);
        qA += __shfl_xor(qA, 16, 64); qA += __shfl_xor(qA, 32, 64);
        sB += __shfl_xor(sB, 16, 64); sB += __shfl_xor(sB, 32, 64);
        qB += __shfl_xor(qB, 16, 64); qB += __shfl_xor(qB, 32, 64);
        if (l < 16) {
            bsum[DJ][l15] = sA; bsum[DJ][16 + l15] = sB;
            bsq[DJ][l15] = qA;  bsq[DJ][16 + l15] = qB;
        }
    }
    __syncthreads();
    if (t < CC) {
        float S = 0.f, Q = 0.f;
#pragma unroll
        for (int w = 0; w < 8; ++w) { S += bsum[w][t]; Q += bsq[w][t]; }
        atomicAdd(&bnacc[t], S);
        atomicAdd(&bnacc[CC + t], Q);
    }
}

// BN + relu -> xbf (bf16) ; per-graph mean/max pool -> feat ; init out1 with bias
__global__ void bn_relu_pool(const float* __restrict__ y, const float* __restrict__ acc,
                             const float* __restrict__ gamma, const float* __restrict__ beta,
                             const float* __restrict__ lin1b,
                             unsigned short* __restrict__ xbf, float* __restrict__ feat,
                             float* __restrict__ out1, int l) {
    int g = blockIdx.x;
    int t = threadIdx.x;          // 128
    if (t < 124) out1[g * 124 + t] = lin1b[t];   // bias init for lin1 atomic accumulate
    int c = t & 31, r0 = t >> 5;
    float mu = acc[c] * (1.f / NN);
    float var = acc[32 + c] * (1.f / NN) - mu * mu;
    float sc = rsqrtf(var + 1e-5f) * gamma[c];
    float bt = beta[c];
    float s = 0.f, mx = -INFINITY;
    for (int r = r0; r < NODES; r += 4) {
        int i = (g * NODES + r) * CC + c;
        float v = (y[i] - mu) * sc + bt;
        v = fmaxf(v, 0.f);
        xbf[i] = f2bf(v);
        s += v; mx = fmaxf(mx, v);
    }
    __shared__ float ls[128], lm[128];
    ls[t] = s; lm[t] = mx;
    __syncthreads();
    if (t < 32) {
        float S = ls[t] + ls[32 + t] + ls[64 + t] + ls[96 + t];
        float M = fmaxf(fmaxf(lm[t], lm[32 + t]), fmaxf(lm[64 + t], lm[96 + t]));
        float* fp = feat + g * FEAT_DIM + NODES + l * 64;
        fp[t] = S * (1.f / NODES);
        fp[32 + t] = M;
    }
}

// ---------------- classifier head ----------------
#define L1_KS 4
#define L1_KC 992    // NC / 4 = 31 K-steps of 32
#define XP 1000      // Xs row stride in shorts
// 4 K-part blocks accumulate into out1 atomically (pre-init'd with bias)
__global__ __launch_bounds__(512) void lin1_mfma(const unsigned short* __restrict__ Xb,
                                                 const unsigned short* __restrict__ WT,
                                                 float* __restrict__ out1) {
    __shared__ unsigned short Xs[16 * XP];   // 32 KB
    int mt = blockIdx.x >> 2, kp = blockIdx.x & 3;
    int t = threadIdx.x;
    int wv = t >> 6, l = t & 63, l15 = l & 15, l4 = l >> 4;
    int M0 = mt * 16, k0 = kp * L1_KC;
    for (int i = t; i < 16 * 124; i += 512) {
        int r = i / 124, c = i - r * 124;
        *(uint4*)&Xs[r * XP + c * 8] = *(const uint4*)&Xb[(size_t)(M0 + r) * NC + k0 + c * 8];
    }
    __syncthreads();
    int N0 = wv * 16;
    f32x4 acc = {0.f, 0.f, 0.f, 0.f};
#pragma unroll 4
    for (int kk = 0; kk < 31; ++kk) {
        bf16x8 a = *(bf16x8*)&Xs[l15 * XP + kk * 32 + l4 * 8];
        bf16x8 b = *(const bf16x8*)&WT[(size_t)(N0 + l15) * NC + k0 + kk * 32 + l4 * 8];
        acc = __builtin_amdgcn_mfma_f32_16x16x32_bf16(a, b, acc, 0, 0, 0);
    }
    if (N0 + l15 < 124) {
#pragma unroll
        for (int r = 0; r < 4; ++r)
            atomicAdd(&out1[(M0 + l4 * 4 + r) * 124 + N0 + l15], acc[r]);
    }
}

__global__ void bn1_relu(const float* __restrict__ out1, const float* __restrict__ gamma,
                         const float* __restrict__ beta, float* __restrict__ feat) {
    __shared__ float ps[4][124], pq[4][124], smu[124], ssc[124], sbt[124];
    int t = threadIdx.x;
    int c = t & 127, seg = t >> 7;
    float s = 0.f, q = 0.f;
    if (c < 124) {
        for (int b = seg * 64; b < seg * 64 + 64; ++b) {
            float v = out1[b * 124 + c]; s += v; q += v * v;
        }
        ps[seg][c] = s; pq[seg][c] = q;
    }
    __syncthreads();
    if (t < 124) {
        float S = ps[0][t] + ps[1][t] + ps[2][t] + ps[3][t];
        float Q = pq[0][t] + pq[1][t] + pq[2][t] + pq[3][t];
        float mu = S * (1.f / NB);
        float var = Q * (1.f / NB) - mu * mu;
        smu[t] = mu; ssc[t] = rsqrtf(var + 1e-5f) * gamma[t]; sbt[t] = beta[t];
    }
    __syncthreads();
    if (c < 124) {
        for (int b = seg * 64; b < seg * 64 + 64; ++b) {
            float v = (out1[b * 124 + c] - smu[c]) * ssc[c] + sbt[c];
            feat[b * FEAT_DIM + c] = fmaxf(v, 0.f);
        }
    }
}

__global__ void lin2_k(const float* __restrict__ feat, const float* __restrict__ W,
                       const float* __restrict__ b, float* __restrict__ out) {
    __shared__ float psum[8][40];
    int g = blockIdx.x;
    int t = threadIdx.x;
    int j = t % 40, u = t / 40;
    if (u < 8) {
        int k0 = u * 40, k1 = (u == 7) ? FEAT_DIM : k0 + 40;
        float s = 0.f;
        for (int k = k0; k < k1; ++k) s += feat[g * FEAT_DIM + k] * W[k * NCLS + j];
        psum[u][j] = s;
    }
    __syncthreads();
    if (t < NCLS) {
        float s = b[t];
#pragma unroll
        for (int u2 = 0; u2 < 8; ++u2) s += psum[u2][t];
        out[g * NCLS + t] = s;
    }
}

extern "C" void kernel_launch(void* const* d_in, const int* in_sizes, int n_in,
                              void* d_out, int out_size, void* d_ws, size_t ws_size,
                              hipStream_t stream) {
    const float* x      = (const float*)d_in[0];
    const int*   ei     = (const int*)d_in[1];
    const float* conv_W = (const float*)d_in[3];
    const float* att_l  = (const float*)d_in[4];
    const float* att_r  = (const float*)d_in[5];
    const float* conv_b = (const float*)d_in[6];
    const float* bn_g   = (const float*)d_in[7];
    const float* bn_b   = (const float*)d_in[8];
    const float* lin1_W = (const float*)d_in[9];
    const float* lin1_b = (const float*)d_in[10];
    const float* bn1_g  = (const float*)d_in[11];
    const float* bn1_b  = (const float*)d_in[12];
    const float* lin2_W = (const float*)d_in[13];
    const float* lin2_b = (const float*)d_in[14];

    float* ws = (float*)d_ws;
    float* y = ws;                                           // NN*32 fp32
    unsigned short* xbf = (unsigned short*)(y + (size_t)NN * CC);   // NN*32 bf16
    float* bnacc = (float*)(xbf + (size_t)NN * CC);          // 192
    float* feat  = bnacc + 192;                              // NB*316
    float* out1  = feat + NB * FEAT_DIM;                     // NB*124
    float* part  = out1 + NB * 124;                          // (unused, layout keep)
    unsigned short* WT = (unsigned short*)(part + L1_KS * NB * 124);  // 128*3968 bf16
    unsigned* gmask = (unsigned*)(WT + (size_t)128 * NC);    // NN*4
    int* gdst  = (int*)(gmask + (size_t)NN * 4);             // NB*132
    int* gdent = gdst + NB * 132;                            // NB*EXCAP

    mask_build<<<NB, 256, 0, stream>>>(ei, gmask, gdst, gdent, bnacc);
    wtrans<<<dim3(NC / 32, 4), 256, 0, stream>>>(lin1_W, WT);

    const float* xin = x;
    for (int l = 0; l < 3; ++l) {
        const float* bnprev = (l == 0) ? nullptr : bnacc + (l - 1) * 64;
        const float* gprev  = (l == 0) ? bn_g : bn_g + (l - 1) * CC;
        const float* bprev  = (l == 0) ? bn_b : bn_b + (l - 1) * CC;
        conv_graph<<<NB, 1024, 0, stream>>>(xin, conv_W + l * CC * HC,
                                            att_l + l * HC, att_r + l * HC,
                                            conv_b + l * CC, gmask, gdst, gdent,
                                            bnprev, gprev, bprev, feat, l - 1,
                                            y, bnacc + l * 64);
        xin = y;
    }

    bn_relu_pool<<<NB, 128, 0, stream>>>(y, bnacc + 128, bn_g + 2 * CC, bn_b + 2 * CC,
                                         lin1_b, xbf, feat, out1, 2);
    lin1_mfma<<<64, 512, 0, stream>>>(xbf, WT, out1);
    bn1_relu<<<1, 512, 0, stream>>>(out1, bn1_g, bn1_b, feat);
    lin2_k<<<NB, 320, 0, stream>>>(feat, lin2_W, lin2_b, (float*)d_out);
}